// Round 3
// baseline (333.310 us; speedup 1.0000x reference)
//
#include <hip/hip_runtime.h>

// CAM module: pre-split x into bf16 hi/lo; energy = q qT (bf16x3, symmetric tiles);
// softmin in-place -> bf16 attn; out = gamma*(attn q) + x.
// B=16, C=512, N=64*64=4096

#define BATCH 16
#define CCH   512
#define NSP   4096

typedef __attribute__((ext_vector_type(8))) short bfx8;
typedef __attribute__((ext_vector_type(4))) short bfx4;
typedef __attribute__((ext_vector_type(4))) float fx4;
typedef __attribute__((ext_vector_type(2))) float fx2;

__device__ __forceinline__ short f2bf(float v) {
    union { float f; unsigned u; } a; a.f = v;
    unsigned r = a.u + 0x7fffu + ((a.u >> 16) & 1u);   // RNE
    return (short)(r >> 16);
}
__device__ __forceinline__ float bf2f(short s) {
    union { unsigned u; float f; } a; a.u = ((unsigned)(unsigned short)s) << 16;
    return a.f;
}
__device__ __forceinline__ short f2bf_trunc(float v) {
    return (short)(__float_as_uint(v) >> 16);
}

// ---------------- Kernel 0: split x -> xh (RNE bf16) + xl (residual bf16) ----------------
__global__ __launch_bounds__(256) void split_kernel(const float* __restrict__ x,
                                                    short* __restrict__ xh,
                                                    short* __restrict__ xl) {
    size_t stride = (size_t)gridDim.x * 256;
    size_t total8 = (size_t)BATCH * CCH * NSP / 8;
    for (size_t u = (size_t)blockIdx.x * 256 + threadIdx.x; u < total8; u += stride) {
        size_t i = u * 8;
        fx4 a = *(const fx4*)(x + i);
        fx4 b = *(const fx4*)(x + i + 4);
        bfx8 h, l;
#pragma unroll
        for (int e = 0; e < 4; ++e) {
            short ha = f2bf(a[e]); h[e]     = ha; l[e]     = f2bf(a[e] - bf2f(ha));
            short hb = f2bf(b[e]); h[e + 4] = hb; l[e + 4] = f2bf(b[e] - bf2f(hb));
        }
        *(bfx8*)(xh + i) = h;
        *(bfx8*)(xl + i) = l;
    }
}

// ---------------- Kernel 1: energy = q qT, bf16x3, symmetric (upper-tri tiles) ----------------
// 64x64 tile, 4 waves (32x32 each), BK=64, chunk swizzle ch^= (r&7).
__global__ __launch_bounds__(256) void energy_kernel(const short* __restrict__ xh,
                                                     const short* __restrict__ xl,
                                                     float* __restrict__ energy) {
    int blk = blockIdx.x;
    int b   = blk / 36;
    int t   = blk % 36;
    int ti = 0, rem = t;
    while (rem >= 8 - ti) { rem -= 8 - ti; ++ti; }
    int tj = ti + rem;
    int c0 = ti * 64, d0 = tj * 64;
    const short* qh = xh + (size_t)b * CCH * NSP;
    const short* ql = xl + (size_t)b * CCH * NSP;

    __shared__ short Ah[64][64];
    __shared__ short Al[64][64];
    __shared__ short Bh[64][64];
    __shared__ short Bl[64][64];

    int tid  = threadIdx.x;
    int lane = tid & 63;
    int w    = tid >> 6;
    int wr   = (w >> 1) * 32;
    int wc   = (w & 1) * 32;

    fx4 acc[2][2];
#pragma unroll
    for (int i = 0; i < 2; i++)
#pragma unroll
        for (int j = 0; j < 2; j++) acc[i][j] = (fx4)(0.0f);

    for (int kt = 0; kt < NSP / 64; ++kt) {
        __syncthreads();
#pragma unroll
        for (int s = 0; s < 2; ++s) {
            int idx = s * 256 + tid;      // 0..511
            int r   = idx >> 3;           // 0..63
            int ch  = idx & 7;            // 16B chunk 0..7
            int chs = (ch ^ (r & 7)) * 8; // swizzled short offset
            size_t ga = (size_t)(c0 + r) * NSP + kt * 64 + ch * 8;
            size_t gb = (size_t)(d0 + r) * NSP + kt * 64 + ch * 8;
            *(bfx8*)&Ah[r][chs] = *(const bfx8*)(qh + ga);
            *(bfx8*)&Al[r][chs] = *(const bfx8*)(ql + ga);
            *(bfx8*)&Bh[r][chs] = *(const bfx8*)(qh + gb);
            *(bfx8*)&Bl[r][chs] = *(const bfx8*)(ql + gb);
        }
        __syncthreads();

        int h = lane >> 4;                // 0..3 (k-quarter within 32-k frag halves)
#pragma unroll
        for (int kk = 0; kk < 2; ++kk) {
            bfx8 ah_[2], al_[2], bh_[2], bl_[2];
#pragma unroll
            for (int mi = 0; mi < 2; ++mi) {
                int r  = wr + mi * 16 + (lane & 15);
                int cc = ((kk * 4 + h) ^ (r & 7)) * 8;
                ah_[mi] = *(const bfx8*)&Ah[r][cc];
                al_[mi] = *(const bfx8*)&Al[r][cc];
            }
#pragma unroll
            for (int ni = 0; ni < 2; ++ni) {
                int r  = wc + ni * 16 + (lane & 15);
                int cc = ((kk * 4 + h) ^ (r & 7)) * 8;
                bh_[ni] = *(const bfx8*)&Bh[r][cc];
                bl_[ni] = *(const bfx8*)&Bl[r][cc];
            }
#pragma unroll
            for (int mi = 0; mi < 2; ++mi)
#pragma unroll
                for (int ni = 0; ni < 2; ++ni) {
                    acc[mi][ni] = __builtin_amdgcn_mfma_f32_16x16x32_bf16(ah_[mi], bh_[ni], acc[mi][ni], 0, 0, 0);
                    acc[mi][ni] = __builtin_amdgcn_mfma_f32_16x16x32_bf16(ah_[mi], bl_[ni], acc[mi][ni], 0, 0, 0);
                    acc[mi][ni] = __builtin_amdgcn_mfma_f32_16x16x32_bf16(al_[mi], bh_[ni], acc[mi][ni], 0, 0, 0);
                }
        }
    }

    // C/D layout: col = lane&15, row = (lane>>4)*4 + reg
    int colw = lane & 15;
    int rowg = (lane >> 4) * 4;
#pragma unroll
    for (int mi = 0; mi < 2; ++mi)
#pragma unroll
        for (int ni = 0; ni < 2; ++ni) {
            int cb = c0 + wr + mi * 16 + rowg;
            int d  = d0 + wc + ni * 16 + colw;
#pragma unroll
            for (int r = 0; r < 4; ++r) {
                int c = cb + r;
                float v = acc[mi][ni][r];
                energy[((size_t)b * CCH + c) * CCH + d] = v;
                if (ti != tj)
                    energy[((size_t)b * CCH + d) * CCH + c] = v;
            }
        }
}

// ---------------- Kernel 2: softmin over rows; writes bf16 attn in-place ----------------
// attn[c,d] = exp(min_d(e) - e[c,d]) / sum, stored bf16 in first 1024B of each 2048B row.
__global__ __launch_bounds__(256) void softmax_kernel(float* __restrict__ energy) {
    size_t row = blockIdx.x;
    float* e = energy + row * CCH;
    int tid = threadIdx.x;
    fx2 v = *(const fx2*)(e + 2 * tid);

    float m = fminf(v[0], v[1]);
#pragma unroll
    for (int off = 32; off; off >>= 1) m = fminf(m, __shfl_xor(m, off));
    __shared__ float redm[4];
    __shared__ float reds[4];
    if ((tid & 63) == 0) redm[tid >> 6] = m;
    __syncthreads();
    m = fminf(fminf(redm[0], redm[1]), fminf(redm[2], redm[3]));

    float w0 = __expf(m - v[0]);
    float w1 = __expf(m - v[1]);
    float s = w0 + w1;
#pragma unroll
    for (int off = 32; off; off >>= 1) s += __shfl_xor(s, off);
    if ((tid & 63) == 0) reds[tid >> 6] = s;
    __syncthreads();
    s = (reds[0] + reds[1]) + (reds[2] + reds[3]);
    float inv = 1.0f / s;
    unsigned uw = ((unsigned)(unsigned short)f2bf(w0 * inv)) |
                  (((unsigned)(unsigned short)f2bf(w1 * inv)) << 16);
    ((unsigned*)e)[tid] = uw;   // safe: all reads completed before the barriers above
}

// ---------------- Kernel 3: out = gamma * (attn @ q) + x ----------------
// BM=64 x BN=128, BK=32. A = bf16 attn (copy). B = xh gathered as u32 n-pairs,
// 16B swizzled ds_writes: chunk = db ^ ((n^(n>>2))&3).
__global__ __launch_bounds__(256) void out_kernel(const float* __restrict__ x,
                                                  const short* __restrict__ xh,
                                                  const short* __restrict__ attnb, // 1024-short row stride
                                                  const float* __restrict__ gamma,
                                                  float* __restrict__ out) {
    int blk = blockIdx.x;
    int b   = blk >> 8;
    int t   = blk & 255;
    int c0  = (t >> 5) * 64;
    int n0  = (t & 31) * 128;
    const float* xb = x + (size_t)b * CCH * NSP;
    const short* qh = xh + (size_t)b * CCH * NSP;
    const short* ab = attnb + (size_t)b * CCH * 1024;

    __shared__ short As[64][32];
    __shared__ short Bs[128][32];
    char* bbase = (char*)&Bs[0][0];

    int tid  = threadIdx.x;
    int lane = tid & 63;
    int w    = tid >> 6;
    int wr   = (w >> 1) * 32;
    int wc   = (w & 1) * 64;

    int p   = tid & 63;                 // n-pair index
    int db  = tid >> 6;                 // d-block 0..3
    int ne  = 2 * p;                    // even n
    int sw0 = (ne ^ (ne >> 2)) & 3;
    int sw1 = ((ne + 1) ^ ((ne + 1) >> 2)) & 3;

    fx4 acc[2][4];
#pragma unroll
    for (int i = 0; i < 2; i++)
#pragma unroll
        for (int j = 0; j < 4; j++) acc[i][j] = (fx4)(0.0f);

    for (int kt = 0; kt < CCH / 32; ++kt) {
        __syncthreads();
        // A: 64x32 bf16 copy
        {
            int r = tid >> 2, c4 = (tid & 3) * 8;
            *(bfx8*)&As[r][c4] = *(const bfx8*)(ab + (size_t)(c0 + r) * 1024 + kt * 32 + c4);
        }
        // B: u32 n-pair gather from xh
        {
            const short* src = qh + (size_t)(kt * 32 + db * 8) * NSP + n0 + ne;
            unsigned wv[8];
#pragma unroll
            for (int i = 0; i < 8; ++i) wv[i] = *(const unsigned*)(src + (size_t)i * NSP);
            bfx8 p0, p1;
#pragma unroll
            for (int i = 0; i < 8; ++i) { p0[i] = (short)(wv[i] & 0xffff); p1[i] = (short)(wv[i] >> 16); }
            *(bfx8*)(bbase + ne * 64 + ((db ^ sw0) << 4)) = p0;
            *(bfx8*)(bbase + (ne + 1) * 64 + ((db ^ sw1) << 4)) = p1;
        }
        __syncthreads();

        bfx8 af[2];
#pragma unroll
        for (int mi = 0; mi < 2; ++mi)
            af[mi] = *(const bfx8*)&As[wr + mi * 16 + (lane & 15)][(lane >> 4) * 8];
        bfx8 bf[4];
#pragma unroll
        for (int ni = 0; ni < 4; ++ni) {
            int n   = wc + ni * 16 + (lane & 15);
            int swn = (n ^ (n >> 2)) & 3;
            bf[ni] = *(const bfx8*)(bbase + n * 64 + (((lane >> 4) ^ swn) << 4));
        }
#pragma unroll
        for (int mi = 0; mi < 2; ++mi)
#pragma unroll
            for (int ni = 0; ni < 4; ++ni)
                acc[mi][ni] = __builtin_amdgcn_mfma_f32_16x16x32_bf16(af[mi], bf[ni], acc[mi][ni], 0, 0, 0);
    }

    float g = gamma[0];
    int colw = lane & 15;
    int rowg = (lane >> 4) * 4;
#pragma unroll
    for (int mi = 0; mi < 2; ++mi)
#pragma unroll
        for (int ni = 0; ni < 4; ++ni) {
            int n = n0 + wc + ni * 16 + colw;
#pragma unroll
            for (int r = 0; r < 4; ++r) {
                int c = c0 + wr + mi * 16 + rowg + r;
                size_t off = ((size_t)b * CCH + c) * NSP + n;
                out[off] = g * acc[mi][ni][r] + xb[(size_t)c * NSP + n];
            }
        }
}

// ================= Fallback path (R2 kernels, used if ws too small) =================
__global__ __launch_bounds__(256) void energy_fb(const float* __restrict__ x,
                                                 float* __restrict__ energy) {
    int blk = blockIdx.x;
    int b   = blk >> 6;
    int t   = blk & 63;
    int c0  = (t >> 3) * 64;
    int d0  = (t & 7) * 64;
    const float* qb = x + (size_t)b * CCH * NSP;
    __shared__ short Ah[64][32];
    __shared__ short Al[64][32];
    __shared__ short Bh[64][32];
    __shared__ short Bl[64][32];
    int tid = threadIdx.x, lane = tid & 63, w = tid >> 6;
    int wr = (w >> 1) * 32, wc = (w & 1) * 32;
    fx4 acc[2][2];
#pragma unroll
    for (int i = 0; i < 2; i++)
#pragma unroll
        for (int j = 0; j < 2; j++) acc[i][j] = (fx4)(0.0f);
    for (int kt = 0; kt < NSP / 32; ++kt) {
        __syncthreads();
#pragma unroll
        for (int s = 0; s < 2; ++s) {
            int idx = s * 256 + tid;
            int r = idx >> 3, f4 = idx & 7;
            fx4 av = *(const fx4*)(qb + (size_t)(c0 + r) * NSP + kt * 32 + f4 * 4);
            fx4 bv = *(const fx4*)(qb + (size_t)(d0 + r) * NSP + kt * 32 + f4 * 4);
            bfx4 ah, al, bh, bl;
#pragma unroll
            for (int e = 0; e < 4; ++e) {
                float vv = av[e]; short hh = f2bf(vv);
                ah[e] = hh; al[e] = f2bf(vv - bf2f(hh));
                vv = bv[e]; hh = f2bf(vv);
                bh[e] = hh; bl[e] = f2bf(vv - bf2f(hh));
            }
            *(bfx4*)&Ah[r][f4 * 4] = ah; *(bfx4*)&Al[r][f4 * 4] = al;
            *(bfx4*)&Bh[r][f4 * 4] = bh; *(bfx4*)&Bl[r][f4 * 4] = bl;
        }
        __syncthreads();
        int rowk = (lane >> 4) * 8;
        bfx8 afh[2], afl[2], bfh[2], bfl[2];
#pragma unroll
        for (int mi = 0; mi < 2; ++mi) {
            int r = wr + mi * 16 + (lane & 15);
            afh[mi] = *(const bfx8*)&Ah[r][rowk];
            afl[mi] = *(const bfx8*)&Al[r][rowk];
        }
#pragma unroll
        for (int ni = 0; ni < 2; ++ni) {
            int r = wc + ni * 16 + (lane & 15);
            bfh[ni] = *(const bfx8*)&Bh[r][rowk];
            bfl[ni] = *(const bfx8*)&Bl[r][rowk];
        }
#pragma unroll
        for (int mi = 0; mi < 2; ++mi)
#pragma unroll
            for (int ni = 0; ni < 2; ++ni) {
                acc[mi][ni] = __builtin_amdgcn_mfma_f32_16x16x32_bf16(afh[mi], bfh[ni], acc[mi][ni], 0, 0, 0);
                acc[mi][ni] = __builtin_amdgcn_mfma_f32_16x16x32_bf16(afh[mi], bfl[ni], acc[mi][ni], 0, 0, 0);
                acc[mi][ni] = __builtin_amdgcn_mfma_f32_16x16x32_bf16(afl[mi], bfh[ni], acc[mi][ni], 0, 0, 0);
            }
    }
    int colw = lane & 15, rowg = (lane >> 4) * 4;
#pragma unroll
    for (int mi = 0; mi < 2; ++mi)
#pragma unroll
        for (int ni = 0; ni < 2; ++ni) {
            int c = c0 + wr + mi * 16 + rowg;
            int d = d0 + wc + ni * 16 + colw;
#pragma unroll
            for (int r = 0; r < 4; ++r)
                energy[((size_t)b * CCH + (c + r)) * CCH + d] = acc[mi][ni][r];
        }
}

__global__ __launch_bounds__(256) void softmax_fb(float* __restrict__ energy) {
    size_t row = blockIdx.x;
    float* e = energy + row * CCH;
    int tid = threadIdx.x;
    float v0 = e[tid], v1 = e[tid + 256];
    float m = fminf(v0, v1);
#pragma unroll
    for (int off = 32; off; off >>= 1) m = fminf(m, __shfl_xor(m, off));
    __shared__ float redm[4];
    __shared__ float reds[4];
    if ((tid & 63) == 0) redm[tid >> 6] = m;
    __syncthreads();
    m = fminf(fminf(redm[0], redm[1]), fminf(redm[2], redm[3]));
    float w0 = __expf(m - v0), w1 = __expf(m - v1);
    float s = w0 + w1;
#pragma unroll
    for (int off = 32; off; off >>= 1) s += __shfl_xor(s, off);
    if ((tid & 63) == 0) reds[tid >> 6] = s;
    __syncthreads();
    s = (reds[0] + reds[1]) + (reds[2] + reds[3]);
    float inv = 1.0f / s;
    e[tid] = w0 * inv; e[tid + 256] = w1 * inv;
}

__global__ __launch_bounds__(256) void out_fb(const float* __restrict__ x,
                                              const float* __restrict__ attn,
                                              const float* __restrict__ gamma,
                                              float* __restrict__ out) {
    int blk = blockIdx.x;
    int b = blk >> 8, t = blk & 255;
    int c0 = (t >> 5) * 64, n0 = (t & 31) * 128;
    const float* qb = x + (size_t)b * CCH * NSP;
    const float* ab = attn + (size_t)b * CCH * CCH;
    __shared__ short As[64][32];
    __shared__ short Bs[128][32];
    char* bbase = (char*)&Bs[0][0];
    int tid = threadIdx.x, lane = tid & 63, w = tid >> 6;
    int wr = (w >> 1) * 32, wc = (w & 1) * 64;
    int bn = tid & 127;
    int bsw = (bn ^ (bn >> 2)) & 3;
    int bdb0 = tid >> 7;
    fx4 acc[2][4];
#pragma unroll
    for (int i = 0; i < 2; i++)
#pragma unroll
        for (int j = 0; j < 4; j++) acc[i][j] = (fx4)(0.0f);
    for (int kt = 0; kt < CCH / 32; ++kt) {
        __syncthreads();
#pragma unroll
        for (int s = 0; s < 2; ++s) {
            int idx = s * 256 + tid;
            int r = idx >> 3, f4 = idx & 7;
            fx4 v = *(const fx4*)(ab + (size_t)(c0 + r) * CCH + kt * 32 + f4 * 4);
            bfx4 hv;
#pragma unroll
            for (int e = 0; e < 4; ++e) hv[e] = f2bf_trunc(v[e]);
            *(bfx4*)&As[r][f4 * 4] = hv;
        }
#pragma unroll
        for (int s = 0; s < 2; ++s) {
            int dblk = bdb0 + 2 * s;
            const float* pp = qb + (size_t)(kt * 32 + dblk * 8) * NSP + n0 + bn;
            float v[8];
#pragma unroll
            for (int i = 0; i < 8; ++i) v[i] = pp[(size_t)i * NSP];
            bfx8 pk;
#pragma unroll
            for (int i = 0; i < 8; ++i) pk[i] = f2bf_trunc(v[i]);
            *(bfx8*)(bbase + bn * 64 + ((dblk ^ bsw) << 4)) = pk;
        }
        __syncthreads();
        bfx8 af[2];
#pragma unroll
        for (int mi = 0; mi < 2; ++mi)
            af[mi] = *(const bfx8*)&As[wr + mi * 16 + (lane & 15)][(lane >> 4) * 8];
        bfx8 bf[4];
#pragma unroll
        for (int ni = 0; ni < 4; ++ni) {
            int n = wc + ni * 16 + (lane & 15);
            int swn = (n ^ (n >> 2)) & 3;
            bf[ni] = *(const bfx8*)(bbase + n * 64 + (((lane >> 4) ^ swn) << 4));
        }
#pragma unroll
        for (int mi = 0; mi < 2; ++mi)
#pragma unroll
            for (int ni = 0; ni < 4; ++ni)
                acc[mi][ni] = __builtin_amdgcn_mfma_f32_16x16x32_bf16(af[mi], bf[ni], acc[mi][ni], 0, 0, 0);
    }
    float g = gamma[0];
    int colw = lane & 15, rowg = (lane >> 4) * 4;
#pragma unroll
    for (int mi = 0; mi < 2; ++mi)
#pragma unroll
        for (int ni = 0; ni < 4; ++ni) {
            int n = n0 + wc + ni * 16 + colw;
#pragma unroll
            for (int r = 0; r < 4; ++r) {
                int c = c0 + wr + mi * 16 + rowg + r;
                out[((size_t)b * CCH + c) * NSP + n] = g * acc[mi][ni][r] + qb[(size_t)c * NSP + n];
            }
        }
}

extern "C" void kernel_launch(void* const* d_in, const int* in_sizes, int n_in,
                              void* d_out, int out_size, void* d_ws, size_t ws_size,
                              hipStream_t stream) {
    (void)in_sizes; (void)n_in; (void)out_size;
    const float* x     = (const float*)d_in[0];
    const float* gamma = (const float*)d_in[1];
    float*       out   = (float*)d_out;

    size_t nel   = (size_t)BATCH * CCH * NSP;            // 33.5M
    size_t bfsz  = nel * sizeof(short);                  // 64 MiB
    size_t esz   = (size_t)BATCH * CCH * CCH * 4;        // 16 MiB
    if (ws_size >= 2 * bfsz + esz) {
        short* xh     = (short*)d_ws;
        short* xl     = (short*)((char*)d_ws + bfsz);
        float* energy = (float*)((char*)d_ws + 2 * bfsz);
        split_kernel  <<<2048, 256, 0, stream>>>(x, xh, xl);
        energy_kernel <<<BATCH * 36, 256, 0, stream>>>(xh, xl, energy);
        softmax_kernel<<<BATCH * CCH, 256, 0, stream>>>(energy);
        out_kernel    <<<BATCH * 256, 256, 0, stream>>>(x, xh, (const short*)energy, gamma, out);
    } else {
        float* energy = (float*)d_ws;
        energy_fb  <<<BATCH * 64, 256, 0, stream>>>(x, energy);
        softmax_fb <<<BATCH * CCH, 256, 0, stream>>>(energy);
        out_fb     <<<BATCH * 256, 256, 0, stream>>>(x, energy, gamma, out);
    }
}

// Round 4
// 271.201 us; speedup vs baseline: 1.2290x; 1.2290x over previous
//
#include <hip/hip_runtime.h>

// CAM module: pre-split x into bf16 hi/lo; energy = q qT (bf16x3, symmetric tiles,
// 2-phase global_load_lds pipeline); softmin in-place -> bf16 attn; out = gamma*(attn q) + x.
// B=16, C=512, N=64*64=4096

#define BATCH 16
#define CCH   512
#define NSP   4096

typedef __attribute__((ext_vector_type(8))) short bfx8;
typedef __attribute__((ext_vector_type(4))) short bfx4;
typedef __attribute__((ext_vector_type(4))) float fx4;
typedef __attribute__((ext_vector_type(2))) float fx2;

__device__ __forceinline__ short f2bf(float v) {
    union { float f; unsigned u; } a; a.f = v;
    unsigned r = a.u + 0x7fffu + ((a.u >> 16) & 1u);   // RNE
    return (short)(r >> 16);
}
__device__ __forceinline__ float bf2f(short s) {
    union { unsigned u; float f; } a; a.u = ((unsigned)(unsigned short)s) << 16;
    return a.f;
}
__device__ __forceinline__ short f2bf_trunc(float v) {
    return (short)(__float_as_uint(v) >> 16);
}

// async global(16B/lane) -> LDS (wave-uniform base + lane*16)
__device__ __forceinline__ void gload16(const short* g, short* l) {
    __builtin_amdgcn_global_load_lds((const __attribute__((address_space(1))) void*)g,
                                     (__attribute__((address_space(3))) void*)l, 16, 0, 0);
}

// ---------------- Kernel 0: split x -> xh (RNE bf16) + xl (residual bf16) ----------------
__global__ __launch_bounds__(256) void split_kernel(const float* __restrict__ x,
                                                    short* __restrict__ xh,
                                                    short* __restrict__ xl) {
    size_t stride = (size_t)gridDim.x * 256;
    size_t total8 = (size_t)BATCH * CCH * NSP / 8;
    for (size_t u = (size_t)blockIdx.x * 256 + threadIdx.x; u < total8; u += stride) {
        size_t i = u * 8;
        fx4 a = *(const fx4*)(x + i);
        fx4 b = *(const fx4*)(x + i + 4);
        bfx8 h, l;
#pragma unroll
        for (int e = 0; e < 4; ++e) {
            short ha = f2bf(a[e]); h[e]     = ha; l[e]     = f2bf(a[e] - bf2f(ha));
            short hb = f2bf(b[e]); h[e + 4] = hb; l[e + 4] = f2bf(b[e] - bf2f(hb));
        }
        *(bfx8*)(xh + i) = h;
        *(bfx8*)(xl + i) = l;
    }
}

// ---------------- Kernel 1: energy = q qT, bf16x3, symmetric tiles, 2-phase pipeline ----------------
// 64x64 tile, 4 waves (32x32 each), BK=64. LDS double-buffered, staged via global_load_lds
// with pre-swizzled source (chunk ch stores global chunk ch^(r&7)).
__global__ __launch_bounds__(256) void energy_kernel(const short* __restrict__ xh,
                                                     const short* __restrict__ xl,
                                                     float* __restrict__ energy) {
    // XCD-chunked bijective swizzle: 576 blocks = 8 xcds x 72 (2 batches each)
    int orig = blockIdx.x;
    int wgid = (orig & 7) * 72 + (orig >> 3);
    int b = wgid / 36;
    int t = wgid % 36;
    int ti = 0, rem = t;
    while (rem >= 8 - ti) { rem -= 8 - ti; ++ti; }
    int tj = ti + rem;
    int c0 = ti * 64, d0 = tj * 64;
    const short* qh = xh + (size_t)b * CCH * NSP;
    const short* ql = xl + (size_t)b * CCH * NSP;

    __shared__ short S[2][4][64][64];   // [buf][Ah,Al,Bh,Bl][row][col]  = 64 KiB

    int tid  = threadIdx.x;
    int lane = tid & 63;
    int w    = tid >> 6;
    int wr   = (w >> 1) * 32;
    int wc   = (w & 1) * 32;

    int srow = lane >> 3;               // 0..7: row within 8-row wave chunk
    int gch  = (lane & 7) ^ srow;       // pre-swizzled source chunk

    auto STAGE = [&](int buf, int kt) {
#pragma unroll
        for (int s = 0; s < 2; ++s) {
            int rg = (s * 4 + w) * 8;   // wave-uniform row group
            int r  = rg + srow;
            size_t koff = (size_t)kt * 64 + gch * 8;
            gload16(qh + (size_t)(c0 + r) * NSP + koff, &S[buf][0][rg][0]);
            gload16(ql + (size_t)(c0 + r) * NSP + koff, &S[buf][1][rg][0]);
            gload16(qh + (size_t)(d0 + r) * NSP + koff, &S[buf][2][rg][0]);
            gload16(ql + (size_t)(d0 + r) * NSP + koff, &S[buf][3][rg][0]);
        }
    };

    fx4 acc[2][2];
#pragma unroll
    for (int i = 0; i < 2; i++)
#pragma unroll
        for (int j = 0; j < 2; j++) acc[i][j] = (fx4)(0.0f);

    STAGE(0, 0);
    __syncthreads();

    int h = lane >> 4;
    int cur = 0;
    const int NT = NSP / 64;
    for (int kt = 0; kt < NT; ++kt) {
        // 1) read all fragments for this K-tile into registers (lgkm deps only)
        bfx8 ah_[2][2], al_[2][2], bh_[2][2], bl_[2][2];   // [kk][mi/ni]
#pragma unroll
        for (int kk = 0; kk < 2; ++kk) {
#pragma unroll
            for (int mi = 0; mi < 2; ++mi) {
                int r  = wr + mi * 16 + (lane & 15);
                int cc = ((kk * 4 + h) ^ (r & 7)) * 8;
                ah_[kk][mi] = *(const bfx8*)&S[cur][0][r][cc];
                al_[kk][mi] = *(const bfx8*)&S[cur][1][r][cc];
            }
#pragma unroll
            for (int ni = 0; ni < 2; ++ni) {
                int r  = wc + ni * 16 + (lane & 15);
                int cc = ((kk * 4 + h) ^ (r & 7)) * 8;
                bh_[kk][ni] = *(const bfx8*)&S[cur][2][r][cc];
                bl_[kk][ni] = *(const bfx8*)&S[cur][3][r][cc];
            }
        }
        // 2) issue next tile's async loads (fly during MFMA below)
        if (kt + 1 < NT) STAGE(cur ^ 1, kt + 1);
        // 3) MFMA
#pragma unroll
        for (int kk = 0; kk < 2; ++kk)
#pragma unroll
            for (int mi = 0; mi < 2; ++mi)
#pragma unroll
                for (int ni = 0; ni < 2; ++ni) {
                    acc[mi][ni] = __builtin_amdgcn_mfma_f32_16x16x32_bf16(ah_[kk][mi], bh_[kk][ni], acc[mi][ni], 0, 0, 0);
                    acc[mi][ni] = __builtin_amdgcn_mfma_f32_16x16x32_bf16(ah_[kk][mi], bl_[kk][ni], acc[mi][ni], 0, 0, 0);
                    acc[mi][ni] = __builtin_amdgcn_mfma_f32_16x16x32_bf16(al_[kk][mi], bh_[kk][ni], acc[mi][ni], 0, 0, 0);
                }
        // 4) drain stage + barrier
        __syncthreads();
        cur ^= 1;
    }

    // C/D layout: col = lane&15, row = (lane>>4)*4 + reg
    int colw = lane & 15;
    int rowg = (lane >> 4) * 4;
#pragma unroll
    for (int mi = 0; mi < 2; ++mi)
#pragma unroll
        for (int ni = 0; ni < 2; ++ni) {
            int cb = c0 + wr + mi * 16 + rowg;
            int d  = d0 + wc + ni * 16 + colw;
#pragma unroll
            for (int r = 0; r < 4; ++r) {
                int c = cb + r;
                float v = acc[mi][ni][r];
                energy[((size_t)b * CCH + c) * CCH + d] = v;
                if (ti != tj)
                    energy[((size_t)b * CCH + d) * CCH + c] = v;
            }
        }
}

// ---------------- Kernel 2: softmin over rows; writes bf16 attn in-place ----------------
__global__ __launch_bounds__(256) void softmax_kernel(float* __restrict__ energy) {
    size_t row = blockIdx.x;
    float* e = energy + row * CCH;
    int tid = threadIdx.x;
    fx2 v = *(const fx2*)(e + 2 * tid);

    float m = fminf(v[0], v[1]);
#pragma unroll
    for (int off = 32; off; off >>= 1) m = fminf(m, __shfl_xor(m, off));
    __shared__ float redm[4];
    __shared__ float reds[4];
    if ((tid & 63) == 0) redm[tid >> 6] = m;
    __syncthreads();
    m = fminf(fminf(redm[0], redm[1]), fminf(redm[2], redm[3]));

    float w0 = __expf(m - v[0]);
    float w1 = __expf(m - v[1]);
    float s = w0 + w1;
#pragma unroll
    for (int off = 32; off; off >>= 1) s += __shfl_xor(s, off);
    if ((tid & 63) == 0) reds[tid >> 6] = s;
    __syncthreads();
    s = (reds[0] + reds[1]) + (reds[2] + reds[3]);
    float inv = 1.0f / s;
    unsigned uw = ((unsigned)(unsigned short)f2bf(w0 * inv)) |
                  (((unsigned)(unsigned short)f2bf(w1 * inv)) << 16);
    ((unsigned*)e)[tid] = uw;   // safe: all reads completed before barriers
}

// ---------------- Kernel 3: out = gamma * (attn @ q) + x ----------------
// BM=64 x BN=128, BK=32. A = bf16 attn copy (As padded to 40 shorts/row — conflict fix).
// B = xh gathered as u32 n-pairs, swizzled 16B ds_writes. T14: loads for kt+1 issued
// before MFMA of kt; LDS writes after barrier.
__global__ __launch_bounds__(256) void out_kernel(const float* __restrict__ x,
                                                  const short* __restrict__ xh,
                                                  const short* __restrict__ attnb, // 1024-short rows
                                                  const float* __restrict__ gamma,
                                                  float* __restrict__ out) {
    // XCD-chunked swizzle: 4096 blocks = 8 x 512 (2 batches per xcd)
    int orig = blockIdx.x;
    int blk  = (orig & 7) * 512 + (orig >> 3);
    int b   = blk >> 8;
    int t   = blk & 255;
    int c0  = (t >> 5) * 64;
    int n0  = (t & 31) * 128;
    const float* xb = x + (size_t)b * CCH * NSP;
    const short* qh = xh + (size_t)b * CCH * NSP;
    const short* ab = attnb + (size_t)b * CCH * 1024;

    __shared__ short As[64][40];        // padded: 80B rows, bank-spread
    __shared__ short Bs[128][32];
    char* bbase = (char*)&Bs[0][0];

    int tid  = threadIdx.x;
    int lane = tid & 63;
    int w    = tid >> 6;
    int wr   = (w >> 1) * 32;
    int wc   = (w & 1) * 64;

    int ar = tid >> 2, ac = (tid & 3) * 8;  // A-stage coords
    int p   = tid & 63;
    int db  = tid >> 6;
    int ne  = 2 * p;
    int sw0 = (ne ^ (ne >> 2)) & 3;
    int sw1 = ((ne + 1) ^ ((ne + 1) >> 2)) & 3;

    fx4 acc[2][4];
#pragma unroll
    for (int i = 0; i < 2; i++)
#pragma unroll
        for (int j = 0; j < 4; j++) acc[i][j] = (fx4)(0.0f);

    // prologue loads for kt=0
    bfx8 areg = *(const bfx8*)(ab + (size_t)(c0 + ar) * 1024 + ac);
    unsigned wv[8];
    {
        const short* src = qh + (size_t)(db * 8) * NSP + n0 + ne;
#pragma unroll
        for (int i = 0; i < 8; ++i) wv[i] = *(const unsigned*)(src + (size_t)i * NSP);
    }

    for (int kt = 0; kt < CCH / 32; ++kt) {
        __syncthreads();                 // close previous MFMA-phase reads
        // write staged regs -> LDS
        *(bfx8*)&As[ar][ac] = areg;
        {
            bfx8 p0, p1;
#pragma unroll
            for (int i = 0; i < 8; ++i) { p0[i] = (short)(wv[i] & 0xffff); p1[i] = (short)(wv[i] >> 16); }
            *(bfx8*)(bbase + ne * 64 + ((db ^ sw0) << 4)) = p0;
            *(bfx8*)(bbase + (ne + 1) * 64 + ((db ^ sw1) << 4)) = p1;
        }
        __syncthreads();
        // issue next tile's global loads (hidden under MFMA below)
        if (kt + 1 < CCH / 32) {
            areg = *(const bfx8*)(ab + (size_t)(c0 + ar) * 1024 + (kt + 1) * 32 + ac);
            const short* src = qh + (size_t)((kt + 1) * 32 + db * 8) * NSP + n0 + ne;
#pragma unroll
            for (int i = 0; i < 8; ++i) wv[i] = *(const unsigned*)(src + (size_t)i * NSP);
        }

        bfx8 af[2];
#pragma unroll
        for (int mi = 0; mi < 2; ++mi)
            af[mi] = *(const bfx8*)&As[wr + mi * 16 + (lane & 15)][(lane >> 4) * 8];
        bfx8 bf[4];
#pragma unroll
        for (int ni = 0; ni < 4; ++ni) {
            int n   = wc + ni * 16 + (lane & 15);
            int swn = (n ^ (n >> 2)) & 3;
            bf[ni] = *(const bfx8*)(bbase + n * 64 + (((lane >> 4) ^ swn) << 4));
        }
#pragma unroll
        for (int mi = 0; mi < 2; ++mi)
#pragma unroll
            for (int ni = 0; ni < 4; ++ni)
                acc[mi][ni] = __builtin_amdgcn_mfma_f32_16x16x32_bf16(af[mi], bf[ni], acc[mi][ni], 0, 0, 0);
    }

    float g = gamma[0];
    int colw = lane & 15;
    int rowg = (lane >> 4) * 4;
#pragma unroll
    for (int mi = 0; mi < 2; ++mi)
#pragma unroll
        for (int ni = 0; ni < 4; ++ni) {
            int n = n0 + wc + ni * 16 + colw;
#pragma unroll
            for (int r = 0; r < 4; ++r) {
                int c = c0 + wr + mi * 16 + rowg + r;
                size_t off = ((size_t)b * CCH + c) * NSP + n;
                out[off] = g * acc[mi][ni][r] + xb[(size_t)c * NSP + n];
            }
        }
}

extern "C" void kernel_launch(void* const* d_in, const int* in_sizes, int n_in,
                              void* d_out, int out_size, void* d_ws, size_t ws_size,
                              hipStream_t stream) {
    (void)in_sizes; (void)n_in; (void)out_size; (void)ws_size;
    const float* x     = (const float*)d_in[0];
    const float* gamma = (const float*)d_in[1];
    float*       out   = (float*)d_out;

    size_t nel  = (size_t)BATCH * CCH * NSP;
    size_t bfsz = nel * sizeof(short);                   // 64 MiB
    short* xhp    = (short*)d_ws;
    short* xlp    = (short*)((char*)d_ws + bfsz);
    float* energy = (float*)((char*)d_ws + 2 * bfsz);    // 16 MiB

    split_kernel  <<<2048, 256, 0, stream>>>(x, xhp, xlp);
    energy_kernel <<<BATCH * 36, 256, 0, stream>>>(xhp, xlp, energy);
    softmax_kernel<<<BATCH * CCH, 256, 0, stream>>>(energy);
    out_kernel    <<<BATCH * 256, 256, 0, stream>>>(x, xhp, (const short*)energy, gamma, out);
}

// Round 5
// 249.652 us; speedup vs baseline: 1.3351x; 1.0863x over previous
//
#include <hip/hip_runtime.h>

// CAM module: pre-split x into bf16 hi/lo; energy = q qT (bf16x3, symmetric tiles,
// BK=32 dbuf global_load_lds, 5-blocks/CU TLP); softmin -> bf16 attn; out = gamma*(attn q) + x.
// B=16, C=512, N=64*64=4096

#define BATCH 16
#define CCH   512
#define NSP   4096

typedef __attribute__((ext_vector_type(8))) short bfx8;
typedef __attribute__((ext_vector_type(4))) short bfx4;
typedef __attribute__((ext_vector_type(4))) float fx4;
typedef __attribute__((ext_vector_type(2))) float fx2;

__device__ __forceinline__ short f2bf(float v) {
    union { float f; unsigned u; } a; a.f = v;
    unsigned r = a.u + 0x7fffu + ((a.u >> 16) & 1u);   // RNE
    return (short)(r >> 16);
}
__device__ __forceinline__ float bf2f(short s) {
    union { unsigned u; float f; } a; a.u = ((unsigned)(unsigned short)s) << 16;
    return a.f;
}
__device__ __forceinline__ short f2bf_trunc(float v) {
    return (short)(__float_as_uint(v) >> 16);
}

// async global(16B/lane) -> LDS (wave-uniform base + lane*16)
__device__ __forceinline__ void gload16(const short* g, short* l) {
    __builtin_amdgcn_global_load_lds((const __attribute__((address_space(1))) void*)g,
                                     (__attribute__((address_space(3))) void*)l, 16, 0, 0);
}

// ---------------- Kernel 0: split x -> xh (RNE bf16) + xl (residual bf16) ----------------
__global__ __launch_bounds__(256) void split_kernel(const float* __restrict__ x,
                                                    short* __restrict__ xh,
                                                    short* __restrict__ xl) {
    size_t stride = (size_t)gridDim.x * 256;
    size_t total8 = (size_t)BATCH * CCH * NSP / 8;
    for (size_t u = (size_t)blockIdx.x * 256 + threadIdx.x; u < total8; u += stride) {
        size_t i = u * 8;
        fx4 a = *(const fx4*)(x + i);
        fx4 b = *(const fx4*)(x + i + 4);
        bfx8 h, l;
#pragma unroll
        for (int e = 0; e < 4; ++e) {
            short ha = f2bf(a[e]); h[e]     = ha; l[e]     = f2bf(a[e] - bf2f(ha));
            short hb = f2bf(b[e]); h[e + 4] = hb; l[e + 4] = f2bf(b[e] - bf2f(hb));
        }
        *(bfx8*)(xh + i) = h;
        *(bfx8*)(xl + i) = l;
    }
}

// ---------------- Kernel 1: energy = q qT, bf16x3, symmetric tiles ----------------
// 64x64 tile, 4 waves (32x32 each), BK=32, LDS 32 KiB dbuf -> up to 5 blocks/CU.
// LDS rows 64B; chunk swizzle slot = h ^ ((r>>1)&3); source pre-swizzled, dest linear.
__global__ __launch_bounds__(256) void energy_kernel(const short* __restrict__ xh,
                                                     const short* __restrict__ xl,
                                                     float* __restrict__ energy) {
    // XCD-chunked bijective swizzle: 576 blocks = 8 xcds x 72 (2 batches each)
    int orig = blockIdx.x;
    int wgid = (orig & 7) * 72 + (orig >> 3);
    int b = wgid / 36;
    int t = wgid % 36;
    int ti = 0, rem = t;
    while (rem >= 8 - ti) { rem -= 8 - ti; ++ti; }
    int tj = ti + rem;
    int c0 = ti * 64, d0 = tj * 64;
    bool diag = (ti == tj);
    const short* qh = xh + (size_t)b * CCH * NSP;
    const short* ql = xl + (size_t)b * CCH * NSP;

    __shared__ short S[2][4][64][32];   // [buf][Ah,Al,Bh,Bl][row][k]  = 32 KiB

    int tid  = threadIdx.x;
    int lane = tid & 63;
    int w    = tid >> 6;
    int wr   = (w >> 1) * 32;
    int wc   = (w & 1) * 32;

    // staging: each wave covers 16 rows (rb..rb+15), 4 lanes/row.
    int rb   = w * 16;
    int srow = lane >> 2;                       // 0..15
    int gch  = (lane & 3) ^ ((lane >> 3) & 3);  // pre-swizzled source chunk

    auto STAGE = [&](int buf, int kt) {
        size_t koff = (size_t)kt * 32 + gch * 8;
        gload16(qh + (size_t)(c0 + rb + srow) * NSP + koff, &S[buf][0][rb][0]);
        gload16(ql + (size_t)(c0 + rb + srow) * NSP + koff, &S[buf][1][rb][0]);
        if (!diag) {
            gload16(qh + (size_t)(d0 + rb + srow) * NSP + koff, &S[buf][2][rb][0]);
            gload16(ql + (size_t)(d0 + rb + srow) * NSP + koff, &S[buf][3][rb][0]);
        }
    };

    fx4 acc[2][2];
#pragma unroll
    for (int i = 0; i < 2; i++)
#pragma unroll
        for (int j = 0; j < 2; j++) acc[i][j] = (fx4)(0.0f);

    STAGE(0, 0);
    __syncthreads();

    const char* Sb = (const char*)&S[0][0][0][0];
    const int bmH = diag ? 0 : 2, bmL = diag ? 1 : 3;
    int h = lane >> 4;                  // k-chunk 0..3
    int cur = 0;
    const int NT = NSP / 32;
    for (int kt = 0; kt < NT; ++kt) {
        // 1) fragment reads (conflict-free: 8 distinct 16B slots per 16-lane group)
        bfx8 ah_[2], al_[2], bh_[2], bl_[2];
        const char* Sc = Sb + cur * (4 * 64 * 64);
#pragma unroll
        for (int mi = 0; mi < 2; ++mi) {
            int r  = wr + mi * 16 + (lane & 15);
            int bo = r * 64 + ((h ^ ((r >> 1) & 3)) << 4);
            ah_[mi] = *(const bfx8*)(Sc + 0 * 4096 + bo);
            al_[mi] = *(const bfx8*)(Sc + 1 * 4096 + bo);
        }
#pragma unroll
        for (int ni = 0; ni < 2; ++ni) {
            int r  = wc + ni * 16 + (lane & 15);
            int bo = r * 64 + ((h ^ ((r >> 1) & 3)) << 4);
            bh_[ni] = *(const bfx8*)(Sc + bmH * 4096 + bo);
            bl_[ni] = *(const bfx8*)(Sc + bmL * 4096 + bo);
        }
        // 2) issue next tile's async loads (in flight during MFMA)
        if (kt + 1 < NT) STAGE(cur ^ 1, kt + 1);
        // 3) MFMA (3 products: hh, hl, lh)
#pragma unroll
        for (int mi = 0; mi < 2; ++mi)
#pragma unroll
            for (int ni = 0; ni < 2; ++ni) {
                acc[mi][ni] = __builtin_amdgcn_mfma_f32_16x16x32_bf16(ah_[mi], bh_[ni], acc[mi][ni], 0, 0, 0);
                acc[mi][ni] = __builtin_amdgcn_mfma_f32_16x16x32_bf16(ah_[mi], bl_[ni], acc[mi][ni], 0, 0, 0);
                acc[mi][ni] = __builtin_amdgcn_mfma_f32_16x16x32_bf16(al_[mi], bh_[ni], acc[mi][ni], 0, 0, 0);
            }
        // 4) drain + swap
        __syncthreads();
        cur ^= 1;
    }

    // C/D layout: col = lane&15, row = (lane>>4)*4 + reg
    int colw = lane & 15;
    int rowg = (lane >> 4) * 4;
#pragma unroll
    for (int mi = 0; mi < 2; ++mi)
#pragma unroll
        for (int ni = 0; ni < 2; ++ni) {
            int cb = c0 + wr + mi * 16 + rowg;
            int d  = d0 + wc + ni * 16 + colw;
#pragma unroll
            for (int r = 0; r < 4; ++r) {
                int c = cb + r;
                float v = acc[mi][ni][r];
                energy[((size_t)b * CCH + c) * CCH + d] = v;
                if (!diag)
                    energy[((size_t)b * CCH + d) * CCH + c] = v;
            }
        }
}

// ---------------- Kernel 2: softmin over rows; writes bf16 attn in-place ----------------
__global__ __launch_bounds__(256) void softmax_kernel(float* __restrict__ energy) {
    size_t row = blockIdx.x;
    float* e = energy + row * CCH;
    int tid = threadIdx.x;
    fx2 v = *(const fx2*)(e + 2 * tid);

    float m = fminf(v[0], v[1]);
#pragma unroll
    for (int off = 32; off; off >>= 1) m = fminf(m, __shfl_xor(m, off));
    __shared__ float redm[4];
    __shared__ float reds[4];
    if ((tid & 63) == 0) redm[tid >> 6] = m;
    __syncthreads();
    m = fminf(fminf(redm[0], redm[1]), fminf(redm[2], redm[3]));

    float w0 = __expf(m - v[0]);
    float w1 = __expf(m - v[1]);
    float s = w0 + w1;
#pragma unroll
    for (int off = 32; off; off >>= 1) s += __shfl_xor(s, off);
    if ((tid & 63) == 0) reds[tid >> 6] = s;
    __syncthreads();
    s = (reds[0] + reds[1]) + (reds[2] + reds[3]);
    float inv = 1.0f / s;
    unsigned uw = ((unsigned)(unsigned short)f2bf(w0 * inv)) |
                  (((unsigned)(unsigned short)f2bf(w1 * inv)) << 16);
    ((unsigned*)e)[tid] = uw;   // safe: all reads completed before barriers
}

// ---------------- Kernel 3: out = gamma * (attn @ q) + x ----------------
// BM=64 x BN=128, BK=32. A = bf16 attn copy (As padded to 40 shorts/row).
// B = xh gathered as u32 n-pairs, swizzled 16B ds_writes. T14 issue-early/write-late.
__global__ __launch_bounds__(256) void out_kernel(const float* __restrict__ x,
                                                  const short* __restrict__ xh,
                                                  const short* __restrict__ attnb, // 1024-short rows
                                                  const float* __restrict__ gamma,
                                                  float* __restrict__ out) {
    // XCD-chunked swizzle: 4096 blocks = 8 x 512 (2 batches per xcd)
    int orig = blockIdx.x;
    int blk  = (orig & 7) * 512 + (orig >> 3);
    int b   = blk >> 8;
    int t   = blk & 255;
    int c0  = (t >> 5) * 64;
    int n0  = (t & 31) * 128;
    const float* xb = x + (size_t)b * CCH * NSP;
    const short* qh = xh + (size_t)b * CCH * NSP;
    const short* ab = attnb + (size_t)b * CCH * 1024;

    __shared__ short As[64][40];        // padded: 80B rows, bank-spread
    __shared__ short Bs[128][32];
    char* bbase = (char*)&Bs[0][0];

    int tid  = threadIdx.x;
    int lane = tid & 63;
    int w    = tid >> 6;
    int wr   = (w >> 1) * 32;
    int wc   = (w & 1) * 64;

    int ar = tid >> 2, ac = (tid & 3) * 8;  // A-stage coords
    int p   = tid & 63;
    int db  = tid >> 6;
    int ne  = 2 * p;
    int sw0 = (ne ^ (ne >> 2)) & 3;
    int sw1 = ((ne + 1) ^ ((ne + 1) >> 2)) & 3;

    fx4 acc[2][4];
#pragma unroll
    for (int i = 0; i < 2; i++)
#pragma unroll
        for (int j = 0; j < 4; j++) acc[i][j] = (fx4)(0.0f);

    // prologue loads for kt=0
    bfx8 areg = *(const bfx8*)(ab + (size_t)(c0 + ar) * 1024 + ac);
    unsigned wv[8];
    {
        const short* src = qh + (size_t)(db * 8) * NSP + n0 + ne;
#pragma unroll
        for (int i = 0; i < 8; ++i) wv[i] = *(const unsigned*)(src + (size_t)i * NSP);
    }

    for (int kt = 0; kt < CCH / 32; ++kt) {
        __syncthreads();                 // close previous MFMA-phase reads
        // write staged regs -> LDS
        *(bfx8*)&As[ar][ac] = areg;
        {
            bfx8 p0, p1;
#pragma unroll
            for (int i = 0; i < 8; ++i) { p0[i] = (short)(wv[i] & 0xffff); p1[i] = (short)(wv[i] >> 16); }
            *(bfx8*)(bbase + ne * 64 + ((db ^ sw0) << 4)) = p0;
            *(bfx8*)(bbase + (ne + 1) * 64 + ((db ^ sw1) << 4)) = p1;
        }
        __syncthreads();
        // issue next tile's global loads (hidden under MFMA below)
        if (kt + 1 < CCH / 32) {
            areg = *(const bfx8*)(ab + (size_t)(c0 + ar) * 1024 + (kt + 1) * 32 + ac);
            const short* src = qh + (size_t)((kt + 1) * 32 + db * 8) * NSP + n0 + ne;
#pragma unroll
            for (int i = 0; i < 8; ++i) wv[i] = *(const unsigned*)(src + (size_t)i * NSP);
        }

        bfx8 af[2];
#pragma unroll
        for (int mi = 0; mi < 2; ++mi)
            af[mi] = *(const bfx8*)&As[wr + mi * 16 + (lane & 15)][(lane >> 4) * 8];
        bfx8 bf[4];
#pragma unroll
        for (int ni = 0; ni < 4; ++ni) {
            int n   = wc + ni * 16 + (lane & 15);
            int swn = (n ^ (n >> 2)) & 3;
            bf[ni] = *(const bfx8*)(bbase + n * 64 + (((lane >> 4) ^ swn) << 4));
        }
#pragma unroll
        for (int mi = 0; mi < 2; ++mi)
#pragma unroll
            for (int ni = 0; ni < 4; ++ni)
                acc[mi][ni] = __builtin_amdgcn_mfma_f32_16x16x32_bf16(af[mi], bf[ni], acc[mi][ni], 0, 0, 0);
    }

    float g = gamma[0];
    int colw = lane & 15;
    int rowg = (lane >> 4) * 4;
#pragma unroll
    for (int mi = 0; mi < 2; ++mi)
#pragma unroll
        for (int ni = 0; ni < 4; ++ni) {
            int n = n0 + wc + ni * 16 + colw;
#pragma unroll
            for (int r = 0; r < 4; ++r) {
                int c = c0 + wr + mi * 16 + rowg + r;
                size_t off = ((size_t)b * CCH + c) * NSP + n;
                out[off] = g * acc[mi][ni][r] + xb[(size_t)c * NSP + n];
            }
        }
}

extern "C" void kernel_launch(void* const* d_in, const int* in_sizes, int n_in,
                              void* d_out, int out_size, void* d_ws, size_t ws_size,
                              hipStream_t stream) {
    (void)in_sizes; (void)n_in; (void)out_size; (void)ws_size;
    const float* x     = (const float*)d_in[0];
    const float* gamma = (const float*)d_in[1];
    float*       out   = (float*)d_out;

    size_t nel  = (size_t)BATCH * CCH * NSP;
    size_t bfsz = nel * sizeof(short);                   // 64 MiB
    short* xhp    = (short*)d_ws;
    short* xlp    = (short*)((char*)d_ws + bfsz);
    float* energy = (float*)((char*)d_ws + 2 * bfsz);    // 16 MiB

    split_kernel  <<<2048, 256, 0, stream>>>(x, xhp, xlp);
    energy_kernel <<<BATCH * 36, 256, 0, stream>>>(xhp, xlp, energy);
    softmax_kernel<<<BATCH * CCH, 256, 0, stream>>>(energy);
    out_kernel    <<<BATCH * 256, 256, 0, stream>>>(x, xhp, (const short*)energy, gamma, out);
}

// Round 6
// 234.867 us; speedup vs baseline: 1.4191x; 1.0630x over previous
//
#include <hip/hip_runtime.h>

// CAM module: pre-split x into bf16 hi/lo; energy = q qT (bf16x3, symmetric tiles,
// BK=32 dbuf global_load_lds); softmin -> bf16 attn; out = gamma*(attn q) + x
// (128x128 tile, parity-balanced LDS writes).
// B=16, C=512, N=64*64=4096

#define BATCH 16
#define CCH   512
#define NSP   4096

typedef __attribute__((ext_vector_type(8))) short bfx8;
typedef __attribute__((ext_vector_type(4))) short bfx4;
typedef __attribute__((ext_vector_type(4))) float fx4;
typedef __attribute__((ext_vector_type(2))) float fx2;

__device__ __forceinline__ short f2bf(float v) {
    union { float f; unsigned u; } a; a.f = v;
    unsigned r = a.u + 0x7fffu + ((a.u >> 16) & 1u);   // RNE
    return (short)(r >> 16);
}
__device__ __forceinline__ float bf2f(short s) {
    union { unsigned u; float f; } a; a.u = ((unsigned)(unsigned short)s) << 16;
    return a.f;
}

// async global(16B/lane) -> LDS (wave-uniform base + lane*16)
__device__ __forceinline__ void gload16(const short* g, short* l) {
    __builtin_amdgcn_global_load_lds((const __attribute__((address_space(1))) void*)g,
                                     (__attribute__((address_space(3))) void*)l, 16, 0, 0);
}

// ---------------- Kernel 0: split x -> xh (RNE bf16) + xl (residual bf16) ----------------
__global__ __launch_bounds__(256) void split_kernel(const float* __restrict__ x,
                                                    short* __restrict__ xh,
                                                    short* __restrict__ xl) {
    size_t stride = (size_t)gridDim.x * 256;
    size_t total8 = (size_t)BATCH * CCH * NSP / 8;
    for (size_t u = (size_t)blockIdx.x * 256 + threadIdx.x; u < total8; u += stride) {
        size_t i = u * 8;
        fx4 a = *(const fx4*)(x + i);
        fx4 b = *(const fx4*)(x + i + 4);
        bfx8 h, l;
#pragma unroll
        for (int e = 0; e < 4; ++e) {
            short ha = f2bf(a[e]); h[e]     = ha; l[e]     = f2bf(a[e] - bf2f(ha));
            short hb = f2bf(b[e]); h[e + 4] = hb; l[e + 4] = f2bf(b[e] - bf2f(hb));
        }
        *(bfx8*)(xh + i) = h;
        *(bfx8*)(xl + i) = l;
    }
}

// ---------------- Kernel 1: energy = q qT, bf16x3, symmetric tiles ----------------
// 64x64 tile, 4 waves (32x32 each), BK=32, LDS 32 KiB dbuf.
__global__ __launch_bounds__(256) void energy_kernel(const short* __restrict__ xh,
                                                     const short* __restrict__ xl,
                                                     float* __restrict__ energy) {
    // XCD-chunked bijective swizzle: 576 blocks = 8 xcds x 72 (2 batches each)
    int orig = blockIdx.x;
    int wgid = (orig & 7) * 72 + (orig >> 3);
    int b = wgid / 36;
    int t = wgid % 36;
    int ti = 0, rem = t;
    while (rem >= 8 - ti) { rem -= 8 - ti; ++ti; }
    int tj = ti + rem;
    int c0 = ti * 64, d0 = tj * 64;
    bool diag = (ti == tj);
    const short* qh = xh + (size_t)b * CCH * NSP;
    const short* ql = xl + (size_t)b * CCH * NSP;

    __shared__ short S[2][4][64][32];   // [buf][Ah,Al,Bh,Bl][row][k]  = 32 KiB

    int tid  = threadIdx.x;
    int lane = tid & 63;
    int w    = tid >> 6;
    int wr   = (w >> 1) * 32;
    int wc   = (w & 1) * 32;

    int rb   = w * 16;
    int srow = lane >> 2;                       // 0..15
    int gch  = (lane & 3) ^ ((lane >> 3) & 3);  // pre-swizzled source chunk

    auto STAGE = [&](int buf, int kt) {
        size_t koff = (size_t)kt * 32 + gch * 8;
        gload16(qh + (size_t)(c0 + rb + srow) * NSP + koff, &S[buf][0][rb][0]);
        gload16(ql + (size_t)(c0 + rb + srow) * NSP + koff, &S[buf][1][rb][0]);
        if (!diag) {
            gload16(qh + (size_t)(d0 + rb + srow) * NSP + koff, &S[buf][2][rb][0]);
            gload16(ql + (size_t)(d0 + rb + srow) * NSP + koff, &S[buf][3][rb][0]);
        }
    };

    fx4 acc[2][2];
#pragma unroll
    for (int i = 0; i < 2; i++)
#pragma unroll
        for (int j = 0; j < 2; j++) acc[i][j] = (fx4)(0.0f);

    STAGE(0, 0);
    __syncthreads();

    const char* Sb = (const char*)&S[0][0][0][0];
    const int bmH = diag ? 0 : 2, bmL = diag ? 1 : 3;
    int h = lane >> 4;                  // k-chunk 0..3
    int cur = 0;
    const int NT = NSP / 32;
    for (int kt = 0; kt < NT; ++kt) {
        bfx8 ah_[2], al_[2], bh_[2], bl_[2];
        const char* Sc = Sb + cur * (4 * 64 * 64);
#pragma unroll
        for (int mi = 0; mi < 2; ++mi) {
            int r  = wr + mi * 16 + (lane & 15);
            int bo = r * 64 + ((h ^ ((r >> 1) & 3)) << 4);
            ah_[mi] = *(const bfx8*)(Sc + 0 * 4096 + bo);
            al_[mi] = *(const bfx8*)(Sc + 1 * 4096 + bo);
        }
#pragma unroll
        for (int ni = 0; ni < 2; ++ni) {
            int r  = wc + ni * 16 + (lane & 15);
            int bo = r * 64 + ((h ^ ((r >> 1) & 3)) << 4);
            bh_[ni] = *(const bfx8*)(Sc + bmH * 4096 + bo);
            bl_[ni] = *(const bfx8*)(Sc + bmL * 4096 + bo);
        }
        if (kt + 1 < NT) STAGE(cur ^ 1, kt + 1);
#pragma unroll
        for (int mi = 0; mi < 2; ++mi)
#pragma unroll
            for (int ni = 0; ni < 2; ++ni) {
                acc[mi][ni] = __builtin_amdgcn_mfma_f32_16x16x32_bf16(ah_[mi], bh_[ni], acc[mi][ni], 0, 0, 0);
                acc[mi][ni] = __builtin_amdgcn_mfma_f32_16x16x32_bf16(ah_[mi], bl_[ni], acc[mi][ni], 0, 0, 0);
                acc[mi][ni] = __builtin_amdgcn_mfma_f32_16x16x32_bf16(al_[mi], bh_[ni], acc[mi][ni], 0, 0, 0);
            }
        __syncthreads();
        cur ^= 1;
    }

    int colw = lane & 15;
    int rowg = (lane >> 4) * 4;
#pragma unroll
    for (int mi = 0; mi < 2; ++mi)
#pragma unroll
        for (int ni = 0; ni < 2; ++ni) {
            int cb = c0 + wr + mi * 16 + rowg;
            int d  = d0 + wc + ni * 16 + colw;
#pragma unroll
            for (int r = 0; r < 4; ++r) {
                int c = cb + r;
                float v = acc[mi][ni][r];
                energy[((size_t)b * CCH + c) * CCH + d] = v;
                if (!diag)
                    energy[((size_t)b * CCH + d) * CCH + c] = v;
            }
        }
}

// ---------------- Kernel 2: softmin over rows; writes bf16 attn in-place ----------------
__global__ __launch_bounds__(256) void softmax_kernel(float* __restrict__ energy) {
    size_t row = blockIdx.x;
    float* e = energy + row * CCH;
    int tid = threadIdx.x;
    fx2 v = *(const fx2*)(e + 2 * tid);

    float m = fminf(v[0], v[1]);
#pragma unroll
    for (int off = 32; off; off >>= 1) m = fminf(m, __shfl_xor(m, off));
    __shared__ float redm[4];
    __shared__ float reds[4];
    if ((tid & 63) == 0) redm[tid >> 6] = m;
    __syncthreads();
    m = fminf(fminf(redm[0], redm[1]), fminf(redm[2], redm[3]));

    float w0 = __expf(m - v[0]);
    float w1 = __expf(m - v[1]);
    float s = w0 + w1;
#pragma unroll
    for (int off = 32; off; off >>= 1) s += __shfl_xor(s, off);
    if ((tid & 63) == 0) reds[tid >> 6] = s;
    __syncthreads();
    s = (reds[0] + reds[1]) + (reds[2] + reds[3]);
    float inv = 1.0f / s;
    unsigned uw = ((unsigned)(unsigned short)f2bf(w0 * inv)) |
                  (((unsigned)(unsigned short)f2bf(w1 * inv)) << 16);
    ((unsigned*)e)[tid] = uw;   // safe: all reads completed before barriers
}

// ---------------- Kernel 3: out = gamma * (attn @ q) + x ----------------
// BM=128 x BN=128, BK=32, 4 waves each owning 64x64 (16 MFMA/wave/K-step).
// A = bf16 attn copy into padded [128][40]. B = xh gathered as u32 n-pairs,
// parity-swapped swizzled 16B ds_writes (all 32 banks per instruction).
__global__ __launch_bounds__(256, 2) void out_kernel(const float* __restrict__ x,
                                                     const short* __restrict__ xh,
                                                     const short* __restrict__ attnb, // 1024-short rows
                                                     const float* __restrict__ gamma,
                                                     float* __restrict__ out) {
    // XCD-chunked swizzle: 2048 blocks = 8 x 256 (2 batches per xcd)
    int orig = blockIdx.x;
    int blk  = (orig & 7) * 256 + (orig >> 3);
    int b   = blk >> 7;                 // 128 blocks per batch
    int t   = blk & 127;
    int c0  = (t >> 5) * 128;           // 4 c-tiles
    int n0  = (t & 31) * 128;           // 32 n-tiles
    const float* xb = x + (size_t)b * CCH * NSP;
    const short* qh = xh + (size_t)b * CCH * NSP;
    const short* ab = attnb + (size_t)b * CCH * 1024;

    __shared__ short As[128][40];       // padded: 80B rows
    __shared__ short Bs[128][32];       // [n][d], 64B rows, swizzled 16B slots
    char* bbase = (char*)&Bs[0][0];

    int tid  = threadIdx.x;
    int lane = tid & 63;
    int w    = tid >> 6;
    int wr   = (w >> 1) * 64;           // c offset of wave
    int wc   = (w & 1) * 64;            // n offset of wave

    int ar = tid >> 1, ac = (tid & 1) * 16;   // A-stage: 2 chunks/thread
    int p   = tid & 63;
    int db  = tid >> 6;
    int ne  = 2 * p;
    int sw0 = (ne ^ (ne >> 2)) & 3;
    int sw1 = ((ne + 1) ^ ((ne + 1) >> 2)) & 3;
    int addrE = ne * 64 + ((db ^ sw0) << 4);        // even-row slot
    int addrO = (ne + 1) * 64 + ((db ^ sw1) << 4);  // odd-row slot
    bool podd = (p & 1);

    fx4 acc[4][4];
#pragma unroll
    for (int i = 0; i < 4; i++)
#pragma unroll
        for (int j = 0; j < 4; j++) acc[i][j] = (fx4)(0.0f);

    // prologue loads for kt=0
    bfx8 areg0 = *(const bfx8*)(ab + (size_t)(c0 + ar) * 1024 + ac);
    bfx8 areg1 = *(const bfx8*)(ab + (size_t)(c0 + ar) * 1024 + ac + 8);
    unsigned wv[8];
    {
        const short* src = qh + (size_t)(db * 8) * NSP + n0 + ne;
#pragma unroll
        for (int i = 0; i < 8; ++i) wv[i] = *(const unsigned*)(src + (size_t)i * NSP);
    }

    for (int kt = 0; kt < CCH / 32; ++kt) {
        __syncthreads();                 // close previous MFMA-phase reads
        // write staged regs -> LDS
        *(bfx8*)&As[ar][ac]     = areg0;
        *(bfx8*)&As[ar][ac + 8] = areg1;
        {
            bfx8 p0, p1;
#pragma unroll
            for (int i = 0; i < 8; ++i) { p0[i] = (short)(wv[i] & 0xffff); p1[i] = (short)(wv[i] >> 16); }
            // parity swap: each instruction touches even rows (banks 0-15) on half
            // the lanes and odd rows (banks 16-31) on the other half.
            int a1 = podd ? addrO : addrE;
            int a2 = podd ? addrE : addrO;
            bfx8 v1 = podd ? p1 : p0;
            bfx8 v2 = podd ? p0 : p1;
            *(bfx8*)(bbase + a1) = v1;
            *(bfx8*)(bbase + a2) = v2;
        }
        __syncthreads();
        // issue next tile's global loads (hidden under MFMA below)
        if (kt + 1 < CCH / 32) {
            areg0 = *(const bfx8*)(ab + (size_t)(c0 + ar) * 1024 + (kt + 1) * 32 + ac);
            areg1 = *(const bfx8*)(ab + (size_t)(c0 + ar) * 1024 + (kt + 1) * 32 + ac + 8);
            const short* src = qh + (size_t)((kt + 1) * 32 + db * 8) * NSP + n0 + ne;
#pragma unroll
            for (int i = 0; i < 8; ++i) wv[i] = *(const unsigned*)(src + (size_t)i * NSP);
        }

        bfx8 af[4];
#pragma unroll
        for (int mi = 0; mi < 4; ++mi)
            af[mi] = *(const bfx8*)&As[wr + mi * 16 + (lane & 15)][(lane >> 4) * 8];
        bfx8 bf[4];
#pragma unroll
        for (int ni = 0; ni < 4; ++ni) {
            int n   = wc + ni * 16 + (lane & 15);
            int swn = (n ^ (n >> 2)) & 3;
            bf[ni] = *(const bfx8*)(bbase + n * 64 + (((lane >> 4) ^ swn) << 4));
        }
#pragma unroll
        for (int mi = 0; mi < 4; ++mi)
#pragma unroll
            for (int ni = 0; ni < 4; ++ni)
                acc[mi][ni] = __builtin_amdgcn_mfma_f32_16x16x32_bf16(af[mi], bf[ni], acc[mi][ni], 0, 0, 0);
    }

    float g = gamma[0];
    int colw = lane & 15;
    int rowg = (lane >> 4) * 4;
#pragma unroll
    for (int mi = 0; mi < 4; ++mi)
#pragma unroll
        for (int ni = 0; ni < 4; ++ni) {
            int n = n0 + wc + ni * 16 + colw;
#pragma unroll
            for (int r = 0; r < 4; ++r) {
                int c = c0 + wr + mi * 16 + rowg + r;
                size_t off = ((size_t)b * CCH + c) * NSP + n;
                out[off] = g * acc[mi][ni][r] + xb[(size_t)c * NSP + n];
            }
        }
}

extern "C" void kernel_launch(void* const* d_in, const int* in_sizes, int n_in,
                              void* d_out, int out_size, void* d_ws, size_t ws_size,
                              hipStream_t stream) {
    (void)in_sizes; (void)n_in; (void)out_size; (void)ws_size;
    const float* x     = (const float*)d_in[0];
    const float* gamma = (const float*)d_in[1];
    float*       out   = (float*)d_out;

    size_t nel  = (size_t)BATCH * CCH * NSP;
    size_t bfsz = nel * sizeof(short);                   // 64 MiB
    short* xhp    = (short*)d_ws;
    short* xlp    = (short*)((char*)d_ws + bfsz);
    float* energy = (float*)((char*)d_ws + 2 * bfsz);    // 16 MiB

    split_kernel  <<<2048, 256, 0, stream>>>(x, xhp, xlp);
    energy_kernel <<<BATCH * 36, 256, 0, stream>>>(xhp, xlp, energy);
    softmax_kernel<<<BATCH * CCH, 256, 0, stream>>>(energy);
    out_kernel    <<<BATCH * 128, 256, 0, stream>>>(x, xhp, (const short*)energy, gamma, out);
}